// Round 6
// baseline (678.589 us; speedup 1.0000x reference)
//
#include <hip/hip_runtime.h>
#include <math.h>

#define TAU_F 32.0f

typedef __attribute__((ext_vector_type(8))) _Float16 half8;
typedef __attribute__((ext_vector_type(2))) __fp16 half2v;
typedef __attribute__((ext_vector_type(4))) float f32x4;

union HU { uint4 u; half8 v; };

// ============ Kernel 1: G partials, fp32 VALU, no atomics (unchanged) ============
// P[ks][192][2048], ks=4. Rows: 0..89 topic, 90..95 zero, 96..185 domain, 186..191 zero.
__global__ __launch_bounds__(256) void gproj2(
    const float* __restrict__ Wt, const float* __restrict__ Wd,
    const float* __restrict__ mem, const int* __restrict__ cat,
    float* __restrict__ P)
{
    __shared__ float Ml[96 * 36];
    __shared__ float Wl[32 * 68];

    const int bid = blockIdx.x;
    const int mat = bid >> 7;
    const int ks  = (bid >> 5) & 3;
    const int ct  = bid & 31;
    const int c0  = ct * 64;
    const int tid = threadIdx.x;
    const float* __restrict__ W = mat ? Wd : Wt;

    const int tr = tid >> 4;
    const int tc = tid & 15;

    float acc[6][4];
    #pragma unroll
    for (int j = 0; j < 6; ++j)
        #pragma unroll
        for (int q = 0; q < 4; ++q) acc[j][q] = 0.f;

    for (int ch = 0; ch < 6; ++ch) {
        __syncthreads();
        #pragma unroll
        for (int p = 0; p < 3; ++p) {
            const int idx = tid + 256 * p;
            const int r   = idx >> 3;
            const int kq  = idx & 7;
            float4 v = make_float4(0.f, 0.f, 0.f, 0.f);
            if (r < 90) {
                const int d = r / 10;
                const int mrow = cat[d] * 10 + (r - d * 10);
                v = *(const float4*)(mem + (size_t)mrow * 768 + ks * 192 + ch * 32 + kq * 4);
            }
            *(float4*)(Ml + r * 36 + kq * 4) = v;
        }
        #pragma unroll
        for (int p = 0; p < 2; ++p) {
            const int idx = tid + 256 * p;
            const int e   = idx >> 4;
            const int c4  = (idx & 15) * 4;
            *(float4*)(Wl + e * 68 + c4) =
                *(const float4*)(W + (size_t)(ks * 192 + ch * 32 + e) * 2048 + c0 + c4);
        }
        __syncthreads();

        #pragma unroll
        for (int e = 0; e < 32; e += 4) {
            float4 m4[6], w4[4];
            #pragma unroll
            for (int j = 0; j < 6; ++j) m4[j] = *(const float4*)(Ml + (tr * 6 + j) * 36 + e);
            #pragma unroll
            for (int q = 0; q < 4; ++q) w4[q] = *(const float4*)(Wl + (e + q) * 68 + tc * 4);
            #pragma unroll
            for (int j = 0; j < 6; ++j) {
                const float mv[4] = {m4[j].x, m4[j].y, m4[j].z, m4[j].w};
                #pragma unroll
                for (int q = 0; q < 4; ++q) {
                    acc[j][0] = fmaf(mv[q], w4[q].x, acc[j][0]);
                    acc[j][1] = fmaf(mv[q], w4[q].y, acc[j][1]);
                    acc[j][2] = fmaf(mv[q], w4[q].z, acc[j][2]);
                    acc[j][3] = fmaf(mv[q], w4[q].w, acc[j][3]);
                }
            }
        }
    }

    #pragma unroll
    for (int j = 0; j < 6; ++j) {
        float4 v = make_float4(acc[j][0], acc[j][1], acc[j][2], acc[j][3]);
        *(float4*)(P + (size_t)ks * 393216 + (size_t)(mat * 96 + tr * 6 + j) * 2048 + c0 + tc * 4) = v;
    }
}

// ============ Kernel 2: reduce partials -> f16 hi/lo, fragment-major (unchanged) ============
// col-frag cf = nq*3+j in 0..11 (0..5 topic, 6..11 domain);
// addr (halves) = ((kc*12 + cf)*2 + plane)*512 + lq*128 + lm*8
// => consecutive cf are 1024 halves apart; planes 512 halves apart.
__global__ __launch_bounds__(256) void split_g3(
    const float* __restrict__ P, unsigned short* __restrict__ gB)
{
    const int u  = blockIdx.x * 256 + threadIdx.x;  // 0..49151
    const int n  = u >> 8;                          // 0..191
    const int k0 = (u & 255) * 8;                   // 0..2040

    float s[8] = {0.f, 0.f, 0.f, 0.f, 0.f, 0.f, 0.f, 0.f};
    #pragma unroll
    for (int ks = 0; ks < 4; ++ks) {
        const float4 a = *(const float4*)(P + (size_t)ks * 393216 + (size_t)n * 2048 + k0);
        const float4 b = *(const float4*)(P + (size_t)ks * 393216 + (size_t)n * 2048 + k0 + 4);
        s[0] += a.x; s[1] += a.y; s[2] += a.z; s[3] += a.w;
        s[4] += b.x; s[5] += b.y; s[6] += b.z; s[7] += b.w;
    }
    union { _Float16 h[8]; uint4 u4; } hi, lo;
    #pragma unroll
    for (int e = 0; e < 8; ++e) {
        const _Float16 h = (_Float16)s[e];   // RNE
        hi.h[e] = h;
        lo.h[e] = (_Float16)(s[e] - (float)h);
    }
    const int kc = k0 >> 5;
    const int lq = (k0 >> 3) & 3;
    const int nq = n / 48;
    const int rm = n - nq * 48;
    const int j  = rm >> 4;
    const int lm = rm & 15;
    const size_t fH = (size_t)((kc * 12 + nq * 3 + j) * 2 + 0) * 512 + lq * 128 + lm * 8;
    const size_t fL = (size_t)((kc * 12 + nq * 3 + j) * 2 + 1) * 512 + lq * 128 + lm * 8;
    *(uint4*)(gB + fH) = hi.u4;
    *(uint4*)(gB + fL) = lo.u4;
}

// ============ Kernel 3: BARRIER-FREE full-K split-f16 MFMA + fused softmax ============
// 256 blocks x 512 thr (8 waves), 64 rows/block, full K=2048, 32 iters of K=64.
// NO LDS AND NO BARRIER IN THE MAIN LOOP: each lane loads its own MFMA A-fragment
// directly from feat (row = l&15 within the wave's 16-row i-block; the 4 role-waves
// of a row-half re-read the same 8 KB/iter -> L1 hits) and converts in-register.
// B fragments load direct gB->reg (prologue + 1-iter-ahead prefetch). Waves are fully
// independent dataflow pipelines until the single pre-epilogue __syncthreads.
// Roles (r = w&3, balanced 24 MFMA/iter; half = w>>2 picks rows 0-31 / 32-63):
//   r<2 : topic frags {2r,2r+1}, 3 split-passes
//   r>=2: topic frag {2+r} (3 passes) + domain frags {6+3(r-2)..+2} (1 pass)
// Per-acc MFMA order identical to the verified R4 kernel => same output values.
__global__ __launch_bounds__(512, 2) void fused_ep(
    const float* __restrict__ feat, const unsigned short* __restrict__ gB,
    float* __restrict__ out)
{
    __shared__ float sc[64 * 193];   // score panel, conflict-free per-row epilogue reads
    __shared__ float ssqS[64];

    const int tid  = threadIdx.x;
    const int row0 = blockIdx.x * 64;

    const int w  = tid >> 6, l = tid & 63;
    const int lm = l & 15,  lq = l >> 4;
    const int half = w >> 2;            // row half: rows half*32 .. half*32+31
    const int r  = w & 3;               // fragment role
    const bool roleT = (r < 2);
    const int cf0 = 2 * r;              // roleT topic frags cf0, cf0+1
    const int tf  = 2 + r;              // roleM topic frag (4 or 5)
    const int db  = 6 + 3 * (r - 2);    // roleM domain frags db..db+2

    f32x4 acc[2][4];
    #pragma unroll
    for (int i = 0; i < 2; ++i)
        #pragma unroll
        for (int j = 0; j < 4; ++j) acc[i][j] = (f32x4)0.f;
    float ssq0 = 0.f, ssq1 = 0.f;

    // A: lane l loads feat[row0 + half*32 + ii*16 + lm][kt*64 + kf*32 + lq*8 .. +8)
    const float* abase = feat + (size_t)(row0 + half * 32 + lm) * 2048 + lq * 8;
    const unsigned short* lB = gB + l * 8;

    // ---- load helpers (all static indexing; wave-uniform branches) ----
    auto loadA = [&](int kt, float4 a[2][2][2]) {
        #pragma unroll
        for (int ii = 0; ii < 2; ++ii)
            #pragma unroll
            for (int kf = 0; kf < 2; ++kf) {
                const float* p = abase + (size_t)ii * 16 * 2048 + kt * 64 + kf * 32;
                a[ii][kf][0] = *(const float4*)(p);
                a[ii][kf][1] = *(const float4*)(p + 4);
            }
    };
    auto loadB = [&](int kt, uint4 b[2][5]) {
        #pragma unroll
        for (int kf = 0; kf < 2; ++kf) {
            if (roleT) {
                const unsigned short* p = lB + (size_t)((2 * kt + kf) * 12 + cf0) * 1024;
                b[kf][0] = *(const uint4*)(p);           // cf0   hi
                b[kf][1] = *(const uint4*)(p + 512);     // cf0   lo
                b[kf][2] = *(const uint4*)(p + 1024);    // cf0+1 hi
                b[kf][3] = *(const uint4*)(p + 1536);    // cf0+1 lo
            } else {
                const unsigned short* pt = lB + (size_t)((2 * kt + kf) * 12 + tf) * 1024;
                b[kf][0] = *(const uint4*)(pt);          // tf hi
                b[kf][1] = *(const uint4*)(pt + 512);    // tf lo
                const unsigned short* pd = lB + (size_t)((2 * kt + kf) * 12 + db) * 1024;
                b[kf][2] = *(const uint4*)(pd);          // db   hi
                b[kf][3] = *(const uint4*)(pd + 1024);   // db+1 hi
                b[kf][4] = *(const uint4*)(pd + 2048);   // db+2 hi
            }
        }
    };
    // fp32x8 -> f16 hi/lo split (RTZ, same as verified cw), fused ssq
    auto conv8 = [](float4 va, float4 vb, half8& oh, half8& ol, float& s) {
        const float xs[8] = {va.x, va.y, va.z, va.w, vb.x, vb.y, vb.z, vb.w};
        union { half2v h2[4]; half8 v; } uh, ul;
        #pragma unroll
        for (int e = 0; e < 4; ++e) {
            const float a = xs[2 * e], b = xs[2 * e + 1];
            s = fmaf(a, a, s); s = fmaf(b, b, s);
            half2v h = __builtin_amdgcn_cvt_pkrtz(a, b);
            uh.h2[e] = h;
            ul.h2[e] = __builtin_amdgcn_cvt_pkrtz(a - (float)h[0], b - (float)h[1]);
        }
        oh = uh.v; ol = ul.v;
    };

    // ---- prologue: A(0), B(0) in flight ----
    float4 a0[2][2][2], a1[2][2][2];
    uint4  b0[2][5],    b1[2][5];
    loadA(0, a0);
    loadB(0, b0);

    for (int kt = 0; kt < 32; ++kt) {
        // 1. prefetch next iteration (rides in flight through this iter's compute)
        if (kt < 31) { loadA(kt + 1, a1); loadB(kt + 1, b1); }

        // 2. convert this iter's A (first use of a0 -> counted vmcnt wait here)
        half8 fh[2][2], fl[2][2];
        #pragma unroll
        for (int ii = 0; ii < 2; ++ii) {
            conv8(a0[ii][0][0], a0[ii][0][1], fh[ii][0], fl[ii][0], ii ? ssq1 : ssq0);
            conv8(a0[ii][1][0], a0[ii][1][1], fh[ii][1], fl[ii][1], ii ? ssq1 : ssq0);
        }

        // 3. MFMA (per-acc order identical to R4)
        if (roleT) {
            #pragma unroll
            for (int kf = 0; kf < 2; ++kf) {
                HU hA, hB, hC, hD;
                hA.u = b0[kf][0]; hB.u = b0[kf][1]; hC.u = b0[kf][2]; hD.u = b0[kf][3];
                #pragma unroll
                for (int ii = 0; ii < 2; ++ii) {
                    acc[ii][0] = __builtin_amdgcn_mfma_f32_16x16x32_f16(fh[ii][kf], hA.v, acc[ii][0], 0, 0, 0);
                    acc[ii][0] = __builtin_amdgcn_mfma_f32_16x16x32_f16(fh[ii][kf], hB.v, acc[ii][0], 0, 0, 0);
                    acc[ii][0] = __builtin_amdgcn_mfma_f32_16x16x32_f16(fl[ii][kf], hA.v, acc[ii][0], 0, 0, 0);
                    acc[ii][1] = __builtin_amdgcn_mfma_f32_16x16x32_f16(fh[ii][kf], hC.v, acc[ii][1], 0, 0, 0);
                    acc[ii][1] = __builtin_amdgcn_mfma_f32_16x16x32_f16(fh[ii][kf], hD.v, acc[ii][1], 0, 0, 0);
                    acc[ii][1] = __builtin_amdgcn_mfma_f32_16x16x32_f16(fl[ii][kf], hC.v, acc[ii][1], 0, 0, 0);
                }
            }
        } else {
            #pragma unroll
            for (int kf = 0; kf < 2; ++kf) {
                HU hA, hB, hC, hD, hE;
                hA.u = b0[kf][0]; hB.u = b0[kf][1]; hC.u = b0[kf][2];
                hD.u = b0[kf][3]; hE.u = b0[kf][4];
                #pragma unroll
                for (int ii = 0; ii < 2; ++ii) {
                    acc[ii][0] = __builtin_amdgcn_mfma_f32_16x16x32_f16(fh[ii][kf], hA.v, acc[ii][0], 0, 0, 0);
                    acc[ii][0] = __builtin_amdgcn_mfma_f32_16x16x32_f16(fh[ii][kf], hB.v, acc[ii][0], 0, 0, 0);
                    acc[ii][0] = __builtin_amdgcn_mfma_f32_16x16x32_f16(fl[ii][kf], hA.v, acc[ii][0], 0, 0, 0);
                    acc[ii][1] = __builtin_amdgcn_mfma_f32_16x16x32_f16(fh[ii][kf], hC.v, acc[ii][1], 0, 0, 0);
                    acc[ii][2] = __builtin_amdgcn_mfma_f32_16x16x32_f16(fh[ii][kf], hD.v, acc[ii][2], 0, 0, 0);
                    acc[ii][3] = __builtin_amdgcn_mfma_f32_16x16x32_f16(fh[ii][kf], hE.v, acc[ii][3], 0, 0, 0);
                }
            }
        }

        // 4. rotate prefetched regs (unused garbage on last iter is never read)
        #pragma unroll
        for (int ii = 0; ii < 2; ++ii)
            #pragma unroll
            for (int kf = 0; kf < 2; ++kf) {
                a0[ii][kf][0] = a1[ii][kf][0];
                a0[ii][kf][1] = a1[ii][kf][1];
            }
        #pragma unroll
        for (int kf = 0; kf < 2; ++kf)
            #pragma unroll
            for (int q = 0; q < 5; ++q) b0[kf][q] = b1[kf][q];
    }

    // ---- scores -> LDS ----
    if (roleT) {
        #pragma unroll
        for (int ii = 0; ii < 2; ++ii)
            #pragma unroll
            for (int f = 0; f < 2; ++f)
                #pragma unroll
                for (int r4 = 0; r4 < 4; ++r4)
                    sc[(half * 32 + ii * 16 + lq * 4 + r4) * 193 + (cf0 + f) * 16 + lm] = acc[ii][f][r4];
    } else {
        #pragma unroll
        for (int ii = 0; ii < 2; ++ii)
            #pragma unroll
            for (int f = 0; f < 4; ++f) {
                const int cf = (f == 0) ? tf : (db + f - 1);
                #pragma unroll
                for (int r4 = 0; r4 < 4; ++r4)
                    sc[(half * 32 + ii * 16 + lq * 4 + r4) * 193 + cf * 16 + lm] = acc[ii][f][r4];
            }
    }

    // ssq: lanes {l, l^16, l^32, l^48} cover the 4 lq col-groups of row (half*32+ii*16+lm)
    ssq0 += __shfl_xor(ssq0, 16, 64);
    ssq0 += __shfl_xor(ssq0, 32, 64);
    ssq1 += __shfl_xor(ssq1, 16, 64);
    ssq1 += __shfl_xor(ssq1, 32, 64);
    if (r == 0 && l < 16) {             // one role-wave per half writes
        ssqS[half * 32 + lm]      = ssq0;
        ssqS[half * 32 + 16 + lm] = ssq1;
    }
    __syncthreads();

    // ---- softmax epilogue: 2 lanes per row (domains 0..4 / 5..8), waves 0-1 ----
    if (tid < 128) {
        const int rr = tid >> 1, hf = tid & 1;
        const int nd = hf ? 4 : 5;
        const int d0 = hf ? 5 : 0;
        const float inv = TAU_F / fmaxf(sqrtf(ssqS[rr]), 1e-12f);
        const float* scr = sc + (size_t)rr * 193;
        float lg[5];
        float dmax = -1e30f;
        #pragma unroll
        for (int dd = 0; dd < 5; ++dd) {
            if (dd < nd) {
                const int d = d0 + dd;
                const float* v = scr + d * 10;          // topic cols 0..89
                const float* u = scr + 96 + d * 10;     // domain cols 96..185
                float mx = v[0];
                #pragma unroll
                for (int m = 1; m < 10; ++m) mx = fmaxf(mx, v[m]);
                float ssum = 0.f, dot = 0.f;
                #pragma unroll
                for (int m = 0; m < 10; ++m) {
                    const float p = __expf((v[m] - mx) * inv);
                    ssum += p;
                    dot = fmaf(p, u[m], dot);
                }
                const float lgt = (dot / ssum) * inv;
                lg[dd] = lgt;
                dmax = fmaxf(dmax, lgt);
            } else {
                lg[dd] = -1e30f;                        // exp -> 0, doesn't affect sums
            }
        }
        dmax = fmaxf(dmax, __shfl_xor(dmax, 1, 64));
        float s2 = 0.f;
        #pragma unroll
        for (int dd = 0; dd < 5; ++dd) {
            const float p = __expf(lg[dd] - dmax);
            lg[dd] = p;
            s2 += p;
        }
        s2 += __shfl_xor(s2, 1, 64);
        const float r2 = 1.0f / s2;
        #pragma unroll
        for (int dd = 0; dd < 5; ++dd)
            if (dd < nd)
                out[(size_t)(row0 + rr) * 9 + d0 + dd] = lg[dd] * r2;
    }
}

extern "C" void kernel_launch(void* const* d_in, const int* in_sizes, int n_in,
                              void* d_out, int out_size, void* d_ws, size_t ws_size,
                              hipStream_t stream) {
    const float* feature = (const float*)d_in[0];
    const float* Wt      = (const float*)d_in[1];
    const float* Wd      = (const float*)d_in[2];
    const float* mem     = (const float*)d_in[3];
    const int*   cat     = (const int*)d_in[4];

    // ws layout: P (6.3 MB) | gB 1.57 MB @50331648
    float* P  = (float*)d_ws;
    unsigned short* gB = (unsigned short*)((char*)d_ws + 50331648);
    float* out = (float*)d_out;

    gproj2<<<256, 256, 0, stream>>>(Wt, Wd, mem, cat, P);
    split_g3<<<192, 256, 0, stream>>>(P, gB);
    fused_ep<<<256, 512, 0, stream>>>(feature, gB, out);
}

// Round 8
// 661.411 us; speedup vs baseline: 1.0260x; 1.0260x over previous
//
#include <hip/hip_runtime.h>
#include <math.h>

#define TAU_F 32.0f

typedef __attribute__((ext_vector_type(8))) _Float16 half8;
typedef __attribute__((ext_vector_type(2))) __fp16 half2v;
typedef __attribute__((ext_vector_type(4))) float f32x4;

union HU { uint4 u; half8 v; };
union H2U { half2v h; unsigned int u; };

__device__ __forceinline__ void sync_lds_only() {
    // CK-style block_sync_lds: drain LDS ops, leave VMEM (vmcnt) in flight.
    asm volatile("s_waitcnt lgkmcnt(0)" ::: "memory");
    __builtin_amdgcn_s_barrier();
}

// ============ Kernel 1: G partials, fp32 VALU, no atomics (unchanged) ============
// P[ks][192][2048], ks=4. Rows: 0..89 topic, 90..95 zero, 96..185 domain, 186..191 zero.
__global__ __launch_bounds__(256) void gproj2(
    const float* __restrict__ Wt, const float* __restrict__ Wd,
    const float* __restrict__ mem, const int* __restrict__ cat,
    float* __restrict__ P)
{
    __shared__ float Ml[96 * 36];
    __shared__ float Wl[32 * 68];

    const int bid = blockIdx.x;
    const int mat = bid >> 7;
    const int ks  = (bid >> 5) & 3;
    const int ct  = bid & 31;
    const int c0  = ct * 64;
    const int tid = threadIdx.x;
    const float* __restrict__ W = mat ? Wd : Wt;

    const int tr = tid >> 4;
    const int tc = tid & 15;

    float acc[6][4];
    #pragma unroll
    for (int j = 0; j < 6; ++j)
        #pragma unroll
        for (int q = 0; q < 4; ++q) acc[j][q] = 0.f;

    for (int ch = 0; ch < 6; ++ch) {
        __syncthreads();
        #pragma unroll
        for (int p = 0; p < 3; ++p) {
            const int idx = tid + 256 * p;
            const int r   = idx >> 3;
            const int kq  = idx & 7;
            float4 v = make_float4(0.f, 0.f, 0.f, 0.f);
            if (r < 90) {
                const int d = r / 10;
                const int mrow = cat[d] * 10 + (r - d * 10);
                v = *(const float4*)(mem + (size_t)mrow * 768 + ks * 192 + ch * 32 + kq * 4);
            }
            *(float4*)(Ml + r * 36 + kq * 4) = v;
        }
        #pragma unroll
        for (int p = 0; p < 2; ++p) {
            const int idx = tid + 256 * p;
            const int e   = idx >> 4;
            const int c4  = (idx & 15) * 4;
            *(float4*)(Wl + e * 68 + c4) =
                *(const float4*)(W + (size_t)(ks * 192 + ch * 32 + e) * 2048 + c0 + c4);
        }
        __syncthreads();

        #pragma unroll
        for (int e = 0; e < 32; e += 4) {
            float4 m4[6], w4[4];
            #pragma unroll
            for (int j = 0; j < 6; ++j) m4[j] = *(const float4*)(Ml + (tr * 6 + j) * 36 + e);
            #pragma unroll
            for (int q = 0; q < 4; ++q) w4[q] = *(const float4*)(Wl + (e + q) * 68 + tc * 4);
            #pragma unroll
            for (int j = 0; j < 6; ++j) {
                const float mv[4] = {m4[j].x, m4[j].y, m4[j].z, m4[j].w};
                #pragma unroll
                for (int q = 0; q < 4; ++q) {
                    acc[j][0] = fmaf(mv[q], w4[q].x, acc[j][0]);
                    acc[j][1] = fmaf(mv[q], w4[q].y, acc[j][1]);
                    acc[j][2] = fmaf(mv[q], w4[q].z, acc[j][2]);
                    acc[j][3] = fmaf(mv[q], w4[q].w, acc[j][3]);
                }
            }
        }
    }

    #pragma unroll
    for (int j = 0; j < 6; ++j) {
        float4 v = make_float4(acc[j][0], acc[j][1], acc[j][2], acc[j][3]);
        *(float4*)(P + (size_t)ks * 393216 + (size_t)(mat * 96 + tr * 6 + j) * 2048 + c0 + tc * 4) = v;
    }
}

// ============ Kernel 2: reduce partials -> f16 hi/lo, fragment-major (unchanged) ============
// col-frag cf = nq*3+j in 0..11 (0..5 topic, 6..11 domain);
// addr (halves) = ((kc*12 + cf)*2 + plane)*512 + lq*128 + lm*8
// => consecutive cf are 1024 halves apart; planes 512 halves apart.
__global__ __launch_bounds__(256) void split_g3(
    const float* __restrict__ P, unsigned short* __restrict__ gB)
{
    const int u  = blockIdx.x * 256 + threadIdx.x;  // 0..49151
    const int n  = u >> 8;                          // 0..191
    const int k0 = (u & 255) * 8;                   // 0..2040

    float s[8] = {0.f, 0.f, 0.f, 0.f, 0.f, 0.f, 0.f, 0.f};
    #pragma unroll
    for (int ks = 0; ks < 4; ++ks) {
        const float4 a = *(const float4*)(P + (size_t)ks * 393216 + (size_t)n * 2048 + k0);
        const float4 b = *(const float4*)(P + (size_t)ks * 393216 + (size_t)n * 2048 + k0 + 4);
        s[0] += a.x; s[1] += a.y; s[2] += a.z; s[3] += a.w;
        s[4] += b.x; s[5] += b.y; s[6] += b.z; s[7] += b.w;
    }
    union { _Float16 h[8]; uint4 u4; } hi, lo;
    #pragma unroll
    for (int e = 0; e < 8; ++e) {
        const _Float16 h = (_Float16)s[e];   // RNE
        hi.h[e] = h;
        lo.h[e] = (_Float16)(s[e] - (float)h);
    }
    const int kc = k0 >> 5;
    const int lq = (k0 >> 3) & 3;
    const int nq = n / 48;
    const int rm = n - nq * 48;
    const int j  = rm >> 4;
    const int lm = rm & 15;
    const size_t fH = (size_t)((kc * 12 + nq * 3 + j) * 2 + 0) * 512 + lq * 128 + lm * 8;
    const size_t fL = (size_t)((kc * 12 + nq * 3 + j) * 2 + 1) * 512 + lq * 128 + lm * 8;
    *(uint4*)(gB + fH) = hi.u4;
    *(uint4*)(gB + fL) = lo.u4;
}

// ============ Kernel 3: M=16, 4 blocks/CU, split-f16 MFMA + fused softmax ============
// 1024 blocks x 256 thr (4 waves), 16 rows/block, full K=2048, 32 iters of K=64.
// 4 independent barrier domains per CU (vs 2 in R4, 1 in R5) hide per-iter latency.
// A: LDS dbuf staging (coalesced float4/thread, in-place reload post-use).
// B: direct gB->reg, SINGLE register set reloaded IN-PLACE after its MFMA use
//    (~0.9-iter in-flight window, no double-buffer registers -> no spill; R6 lesson).
// Roles (w=0..3, balanced 12 MFMA/iter each; all waves compute the same 16 rows):
//   w<2 : topic frags {2w,2w+1}, 3 split-passes
//   w>=2: topic frag {2+w} (3 passes) + domain frags {6+3(w-2)..+2} (1 pass)
// Per-acc MFMA chain identical to the verified R4 kernel => same score values.
__global__ __launch_bounds__(256, 4) void fused_ep(
    const float* __restrict__ feat, const unsigned short* __restrict__ gB,
    float* __restrict__ out)
{
    // aS: [buf2][plane2][kf2][row16][40] halves = 10,240 B (A staging, dbuf)
    // sc: [16][193] floats = 12,352 B  (aliases aS after the loop)
    __shared__ __align__(16) unsigned char smraw[12352];
    unsigned short* aS = (unsigned short*)smraw;
    float* sc = (float*)smraw;
    __shared__ float ssqS[16];

    const int tid  = threadIdx.x;
    const int row0 = blockIdx.x * 16;

    const int w  = tid >> 6, l = tid & 63;
    const int lm = l & 15,  lq = l >> 4;
    const bool roleT = (w < 2);
    const int cf0 = 2 * w;              // roleT topic frags cf0, cf0+1
    const int tf  = 2 + w;              // roleM topic frag (4 or 5)
    const int db  = 6 + 3 * (w - 2);    // roleM domain frags db..db+2
    const int sr = tid >> 4, kq = tid & 15;  // A staging: row 0..15, k-quad 0..15
    const int skf = kq >> 3, sk4 = kq & 7;   // kf half, 4-float group within half

    f32x4 acc[4];
    #pragma unroll
    for (int j = 0; j < 4; ++j) acc[j] = (f32x4)0.f;
    float ssq = 0.f;

    const float* fbase = feat + (size_t)(row0 + sr) * 2048 + kq * 4;
    const unsigned short* lB = gB + l * 8;

    // convert+stage A (one float4/thread): fp32 -> f16 hi/lo planes, fused ssq
    auto cw = [&](int buf, float4 v) {
        ssq = fmaf(v.x, v.x, ssq); ssq = fmaf(v.y, v.y, ssq);
        ssq = fmaf(v.z, v.z, ssq); ssq = fmaf(v.w, v.w, ssq);
        H2U h0, h1, l0, l1;
        h0.h = __builtin_amdgcn_cvt_pkrtz(v.x, v.y);
        h1.h = __builtin_amdgcn_cvt_pkrtz(v.z, v.w);
        l0.h = __builtin_amdgcn_cvt_pkrtz(v.x - (float)h0.h[0], v.y - (float)h0.h[1]);
        l1.h = __builtin_amdgcn_cvt_pkrtz(v.z - (float)h1.h[0], v.w - (float)h1.h[1]);
        uint2 hi; hi.x = h0.u; hi.y = h1.u;
        uint2 lo; lo.x = l0.u; lo.y = l1.u;
        *(uint2*)(aS + (size_t)(((buf * 2 + 0) * 2 + skf) * 16 + sr) * 40 + sk4 * 4) = hi;
        *(uint2*)(aS + (size_t)(((buf * 2 + 1) * 2 + skf) * 16 + sr) * 40 + sk4 * 4) = lo;
    };

    auto loadB = [&](int kt, uint4 b[2][5]) {
        #pragma unroll
        for (int kf = 0; kf < 2; ++kf) {
            const unsigned short* bk = lB + (size_t)(2 * kt + kf) * 12288;
            if (roleT) {
                const unsigned short* p = bk + (size_t)cf0 * 1024;
                b[kf][0] = *(const uint4*)(p);           // cf0   hi
                b[kf][1] = *(const uint4*)(p + 512);     // cf0   lo
                b[kf][2] = *(const uint4*)(p + 1024);    // cf0+1 hi
                b[kf][3] = *(const uint4*)(p + 1536);    // cf0+1 lo
            } else {
                const unsigned short* pt = bk + (size_t)tf * 1024;
                b[kf][0] = *(const uint4*)(pt);          // tf hi
                b[kf][1] = *(const uint4*)(pt + 512);    // tf lo
                const unsigned short* pd = bk + (size_t)db * 1024;
                b[kf][2] = *(const uint4*)(pd);          // db   hi
                b[kf][3] = *(const uint4*)(pd + 1024);   // db+1 hi
                b[kf][4] = *(const uint4*)(pd + 2048);   // db+2 hi
            }
        }
    };

    // ---- prologue: stage A(0); A(1) and B(0) in flight ----
    uint4  b[2][5];
    {
        float4 c0 = *(const float4*)(fbase);
        loadB(0, b);
        cw(0, c0);
    }
    float4 c1 = *(const float4*)(fbase + 64);
    sync_lds_only();

    for (int kt = 0; kt < 32; ++kt) {
        const int cb = kt & 1;

        // stage A(kt+1) into the other buffer (c1 loaded one iter ago)
        if (kt < 31) cw((kt + 1) & 1, c1);

        // A fragments from aS[cb]
        half8 fh[2], fl[2];
        #pragma unroll
        for (int kf = 0; kf < 2; ++kf) {
            HU th, tl;
            th.u = *(const uint4*)(aS + (size_t)(((cb * 2 + 0) * 2 + kf) * 16 + lm) * 40 + lq * 8);
            tl.u = *(const uint4*)(aS + (size_t)(((cb * 2 + 1) * 2 + kf) * 16 + lm) * 40 + lq * 8);
            fh[kf] = th.v;
            fl[kf] = tl.v;
        }

        // MFMA (per-acc order identical to R4)
        if (roleT) {
            #pragma unroll
            for (int kf = 0; kf < 2; ++kf) {
                HU hA, hB, hC, hD;
                hA.u = b[kf][0]; hB.u = b[kf][1]; hC.u = b[kf][2]; hD.u = b[kf][3];
                acc[0] = __builtin_amdgcn_mfma_f32_16x16x32_f16(fh[kf], hA.v, acc[0], 0, 0, 0);
                acc[0] = __builtin_amdgcn_mfma_f32_16x16x32_f16(fh[kf], hB.v, acc[0], 0, 0, 0);
                acc[0] = __builtin_amdgcn_mfma_f32_16x16x32_f16(fl[kf], hA.v, acc[0], 0, 0, 0);
                acc[1] = __builtin_amdgcn_mfma_f32_16x16x32_f16(fh[kf], hC.v, acc[1], 0, 0, 0);
                acc[1] = __builtin_amdgcn_mfma_f32_16x16x32_f16(fh[kf], hD.v, acc[1], 0, 0, 0);
                acc[1] = __builtin_amdgcn_mfma_f32_16x16x32_f16(fl[kf], hC.v, acc[1], 0, 0, 0);
            }
        } else {
            #pragma unroll
            for (int kf = 0; kf < 2; ++kf) {
                HU hA, hB, hC, hD, hE;
                hA.u = b[kf][0]; hB.u = b[kf][1]; hC.u = b[kf][2];
                hD.u = b[kf][3]; hE.u = b[kf][4];
                acc[0] = __builtin_amdgcn_mfma_f32_16x16x32_f16(fh[kf], hA.v, acc[0], 0, 0, 0);
                acc[0] = __builtin_amdgcn_mfma_f32_16x16x32_f16(fh[kf], hB.v, acc[0], 0, 0, 0);
                acc[0] = __builtin_amdgcn_mfma_f32_16x16x32_f16(fl[kf], hA.v, acc[0], 0, 0, 0);
                acc[1] = __builtin_amdgcn_mfma_f32_16x16x32_f16(fh[kf], hC.v, acc[1], 0, 0, 0);
                acc[2] = __builtin_amdgcn_mfma_f32_16x16x32_f16(fh[kf], hD.v, acc[2], 0, 0, 0);
                acc[3] = __builtin_amdgcn_mfma_f32_16x16x32_f16(fh[kf], hE.v, acc[3], 0, 0, 0);
            }
        }

        // in-place reloads for the NEXT iterations (issued after last use; ride
        // through the barrier — sync_lds_only never drains vmcnt)
        if (kt < 31) {
            loadB(kt + 1, b);                                   // consumed in kt+1
            const int ka = (kt + 2 < 32) ? kt + 2 : 31;
            c1 = *(const float4*)(fbase + ka * 64);             // staged in kt+1
        }

        sync_lds_only();
    }

    // ---- scores -> LDS (aliases aS; safe after final barrier) ----
    if (roleT) {
        #pragma unroll
        for (int f = 0; f < 2; ++f)
            #pragma unroll
            for (int r4 = 0; r4 < 4; ++r4)
                sc[(lq * 4 + r4) * 193 + (cf0 + f) * 16 + lm] = acc[f][r4];
    } else {
        #pragma unroll
        for (int f = 0; f < 4; ++f) {
            const int cf = (f == 0) ? tf : (db + f - 1);
            #pragma unroll
            for (int r4 = 0; r4 < 4; ++r4)
                sc[(lq * 4 + r4) * 193 + cf * 16 + lm] = acc[f][r4];
        }
    }

    // ssq: 16 staging threads per row (kq 0..15) -> full-row |feat|^2
    ssq += __shfl_xor(ssq, 1, 64);
    ssq += __shfl_xor(ssq, 2, 64);
    ssq += __shfl_xor(ssq, 4, 64);
    ssq += __shfl_xor(ssq, 8, 64);
    if ((l & 15) == 0) ssqS[w * 4 + (l >> 4)] = ssq;
    __syncthreads();

    // ---- softmax epilogue: 2 lanes per row (domains 0..4 / 5..8), wave 0 ----
    if (tid < 32) {
        const int rr = tid >> 1, hf = tid & 1;
        const int nd = hf ? 4 : 5;
        const int d0 = hf ? 5 : 0;
        const float inv = TAU_F / fmaxf(sqrtf(ssqS[rr]), 1e-12f);
        const float* scr = sc + (size_t)rr * 193;
        float lg[5];
        float dmax = -1e30f;
        #pragma unroll
        for (int dd = 0; dd < 5; ++dd) {
            if (dd < nd) {
                const int d = d0 + dd;
                const float* v = scr + d * 10;          // topic cols 0..89
                const float* u = scr + 96 + d * 10;     // domain cols 96..185
                float mx = v[0];
                #pragma unroll
                for (int m = 1; m < 10; ++m) mx = fmaxf(mx, v[m]);
                float ssum = 0.f, dot = 0.f;
                #pragma unroll
                for (int m = 0; m < 10; ++m) {
                    const float p = __expf((v[m] - mx) * inv);
                    ssum += p;
                    dot = fmaf(p, u[m], dot);
                }
                const float lgt = (dot / ssum) * inv;
                lg[dd] = lgt;
                dmax = fmaxf(dmax, lgt);
            } else {
                lg[dd] = -1e30f;                        // exp -> 0, doesn't affect sums
            }
        }
        dmax = fmaxf(dmax, __shfl_xor(dmax, 1, 64));
        float s2 = 0.f;
        #pragma unroll
        for (int dd = 0; dd < 5; ++dd) {
            const float p = __expf(lg[dd] - dmax);
            lg[dd] = p;
            s2 += p;
        }
        s2 += __shfl_xor(s2, 1, 64);
        const float r2 = 1.0f / s2;
        #pragma unroll
        for (int dd = 0; dd < 5; ++dd)
            if (dd < nd)
                out[(size_t)(row0 + rr) * 9 + d0 + dd] = lg[dd] * r2;
    }
}

extern "C" void kernel_launch(void* const* d_in, const int* in_sizes, int n_in,
                              void* d_out, int out_size, void* d_ws, size_t ws_size,
                              hipStream_t stream) {
    const float* feature = (const float*)d_in[0];
    const float* Wt      = (const float*)d_in[1];
    const float* Wd      = (const float*)d_in[2];
    const float* mem     = (const float*)d_in[3];
    const int*   cat     = (const int*)d_in[4];

    // ws layout: P (6.3 MB) | gB 1.57 MB @50331648
    float* P  = (float*)d_ws;
    unsigned short* gB = (unsigned short*)((char*)d_ws + 50331648);
    float* out = (float*)d_out;

    gproj2<<<256, 256, 0, stream>>>(Wt, Wd, mem, cat, P);
    split_g3<<<192, 256, 0, stream>>>(P, gB);
    fused_ep<<<1024, 256, 0, stream>>>(feature, gB, out);
}

// Round 9
// 278.997 us; speedup vs baseline: 2.4322x; 2.3707x over previous
//
#include <hip/hip_runtime.h>
#include <math.h>

#define TAU_F 32.0f

typedef __attribute__((ext_vector_type(8))) _Float16 half8;
typedef __attribute__((ext_vector_type(2))) __fp16 half2v;
typedef __attribute__((ext_vector_type(4))) float f32x4;

union HU { uint4 u; half8 v; };
union H2U { half2v h; unsigned int u; };

__device__ __forceinline__ void sync_lds_only() {
    // CK-style block_sync_lds: drain LDS ops, leave VMEM (vmcnt) in flight.
    asm volatile("s_waitcnt lgkmcnt(0)" ::: "memory");
    __builtin_amdgcn_s_barrier();
}

// ============ Kernel 1: G partials, fp32 VALU, no atomics (unchanged) ============
// P[ks][192][2048], ks=4. Rows: 0..89 topic, 90..95 zero, 96..185 domain, 186..191 zero.
__global__ __launch_bounds__(256) void gproj2(
    const float* __restrict__ Wt, const float* __restrict__ Wd,
    const float* __restrict__ mem, const int* __restrict__ cat,
    float* __restrict__ P)
{
    __shared__ float Ml[96 * 36];
    __shared__ float Wl[32 * 68];

    const int bid = blockIdx.x;
    const int mat = bid >> 7;
    const int ks  = (bid >> 5) & 3;
    const int ct  = bid & 31;
    const int c0  = ct * 64;
    const int tid = threadIdx.x;
    const float* __restrict__ W = mat ? Wd : Wt;

    const int tr = tid >> 4;
    const int tc = tid & 15;

    float acc[6][4];
    #pragma unroll
    for (int j = 0; j < 6; ++j)
        #pragma unroll
        for (int q = 0; q < 4; ++q) acc[j][q] = 0.f;

    for (int ch = 0; ch < 6; ++ch) {
        __syncthreads();
        #pragma unroll
        for (int p = 0; p < 3; ++p) {
            const int idx = tid + 256 * p;
            const int r   = idx >> 3;
            const int kq  = idx & 7;
            float4 v = make_float4(0.f, 0.f, 0.f, 0.f);
            if (r < 90) {
                const int d = r / 10;
                const int mrow = cat[d] * 10 + (r - d * 10);
                v = *(const float4*)(mem + (size_t)mrow * 768 + ks * 192 + ch * 32 + kq * 4);
            }
            *(float4*)(Ml + r * 36 + kq * 4) = v;
        }
        #pragma unroll
        for (int p = 0; p < 2; ++p) {
            const int idx = tid + 256 * p;
            const int e   = idx >> 4;
            const int c4  = (idx & 15) * 4;
            *(float4*)(Wl + e * 68 + c4) =
                *(const float4*)(W + (size_t)(ks * 192 + ch * 32 + e) * 2048 + c0 + c4);
        }
        __syncthreads();

        #pragma unroll
        for (int e = 0; e < 32; e += 4) {
            float4 m4[6], w4[4];
            #pragma unroll
            for (int j = 0; j < 6; ++j) m4[j] = *(const float4*)(Ml + (tr * 6 + j) * 36 + e);
            #pragma unroll
            for (int q = 0; q < 4; ++q) w4[q] = *(const float4*)(Wl + (e + q) * 68 + tc * 4);
            #pragma unroll
            for (int j = 0; j < 6; ++j) {
                const float mv[4] = {m4[j].x, m4[j].y, m4[j].z, m4[j].w};
                #pragma unroll
                for (int q = 0; q < 4; ++q) {
                    acc[j][0] = fmaf(mv[q], w4[q].x, acc[j][0]);
                    acc[j][1] = fmaf(mv[q], w4[q].y, acc[j][1]);
                    acc[j][2] = fmaf(mv[q], w4[q].z, acc[j][2]);
                    acc[j][3] = fmaf(mv[q], w4[q].w, acc[j][3]);
                }
            }
        }
    }

    #pragma unroll
    for (int j = 0; j < 6; ++j) {
        float4 v = make_float4(acc[j][0], acc[j][1], acc[j][2], acc[j][3]);
        *(float4*)(P + (size_t)ks * 393216 + (size_t)(mat * 96 + tr * 6 + j) * 2048 + c0 + tc * 4) = v;
    }
}

// ============ Kernel 2: reduce partials -> f16 hi/lo, fragment-major (unchanged) ============
// col-frag cf = nq*3+j in 0..11 (0..5 topic, 6..11 domain);
// addr (halves) = ((kc*12 + cf)*2 + plane)*512 + lq*128 + lm*8
// => consecutive cf are 1024 halves apart; planes 512 halves apart.
__global__ __launch_bounds__(256) void split_g3(
    const float* __restrict__ P, unsigned short* __restrict__ gB)
{
    const int u  = blockIdx.x * 256 + threadIdx.x;  // 0..49151
    const int n  = u >> 8;                          // 0..191
    const int k0 = (u & 255) * 8;                   // 0..2040

    float s[8] = {0.f, 0.f, 0.f, 0.f, 0.f, 0.f, 0.f, 0.f};
    #pragma unroll
    for (int ks = 0; ks < 4; ++ks) {
        const float4 a = *(const float4*)(P + (size_t)ks * 393216 + (size_t)n * 2048 + k0);
        const float4 b = *(const float4*)(P + (size_t)ks * 393216 + (size_t)n * 2048 + k0 + 4);
        s[0] += a.x; s[1] += a.y; s[2] += a.z; s[3] += a.w;
        s[4] += b.x; s[5] += b.y; s[6] += b.z; s[7] += b.w;
    }
    union { _Float16 h[8]; uint4 u4; } hi, lo;
    #pragma unroll
    for (int e = 0; e < 8; ++e) {
        const _Float16 h = (_Float16)s[e];   // RNE
        hi.h[e] = h;
        lo.h[e] = (_Float16)(s[e] - (float)h);
    }
    const int kc = k0 >> 5;
    const int lq = (k0 >> 3) & 3;
    const int nq = n / 48;
    const int rm = n - nq * 48;
    const int j  = rm >> 4;
    const int lm = rm & 15;
    const size_t fH = (size_t)((kc * 12 + nq * 3 + j) * 2 + 0) * 512 + lq * 128 + lm * 8;
    const size_t fL = (size_t)((kc * 12 + nq * 3 + j) * 2 + 1) * 512 + lq * 128 + lm * 8;
    *(uint4*)(gB + fH) = hi.u4;
    *(uint4*)(gB + fL) = lo.u4;
}

// ============ Kernel 3: M=16, 4 blocks/CU, split-f16 MFMA + fused softmax ============
// 1024 blocks x 256 thr (4 waves), 16 rows/block, full K=2048, 32 iters of K=64.
// 4 independent barrier domains per CU hide the per-iter latency chain (R4/R5 lesson).
// R8 BUGFIX (structural): B lived in a uint4[2][5] passed as a lambda array-param ->
// pointer decay defeated SROA -> 40-reg kernel + 1.08 GB scratch traffic. B is now
// TEN NAMED uint4 LOCALS loaded via macro (all static) — nothing can hit scratch.
// Roles (w=0..3, balanced 12 MFMA/iter each; all waves compute the same 16 rows):
//   w<2 : topic frags {2w,2w+1}, 3 split-passes
//   w>=2: topic frag {2+w} (3 passes) + domain frags {6+3(w-2)..+2} (1 pass)
// Per-acc MFMA chain identical to the verified R4 kernel => same score values.
#define LOADB(ktv)                                                              \
    do {                                                                        \
        const unsigned short* bk0 = lB + (size_t)(2 * (ktv)) * 12288;           \
        const unsigned short* bk1 = bk0 + 12288;                                \
        if (roleT) {                                                            \
            const unsigned short* p0 = bk0 + (size_t)cf0 * 1024;                \
            const unsigned short* p1 = bk1 + (size_t)cf0 * 1024;                \
            b00 = *(const uint4*)(p0);                                          \
            b01 = *(const uint4*)(p0 + 512);                                    \
            b02 = *(const uint4*)(p0 + 1024);                                   \
            b03 = *(const uint4*)(p0 + 1536);                                   \
            b10 = *(const uint4*)(p1);                                          \
            b11 = *(const uint4*)(p1 + 512);                                    \
            b12 = *(const uint4*)(p1 + 1024);                                   \
            b13 = *(const uint4*)(p1 + 1536);                                   \
        } else {                                                                \
            const unsigned short* pt0 = bk0 + (size_t)tf * 1024;                \
            const unsigned short* pt1 = bk1 + (size_t)tf * 1024;                \
            const unsigned short* pd0 = bk0 + (size_t)db * 1024;                \
            const unsigned short* pd1 = bk1 + (size_t)db * 1024;                \
            b00 = *(const uint4*)(pt0);                                         \
            b01 = *(const uint4*)(pt0 + 512);                                   \
            b02 = *(const uint4*)(pd0);                                         \
            b03 = *(const uint4*)(pd0 + 1024);                                  \
            b04 = *(const uint4*)(pd0 + 2048);                                  \
            b10 = *(const uint4*)(pt1);                                         \
            b11 = *(const uint4*)(pt1 + 512);                                   \
            b12 = *(const uint4*)(pd1);                                         \
            b13 = *(const uint4*)(pd1 + 1024);                                  \
            b14 = *(const uint4*)(pd1 + 2048);                                  \
        }                                                                       \
    } while (0)

__global__ __launch_bounds__(256, 4) void fused_ep(
    const float* __restrict__ feat, const unsigned short* __restrict__ gB,
    float* __restrict__ out)
{
    // aS: [buf2][plane2][kf2][row16][40] halves = 10,240 B (A staging, dbuf)
    // sc: [16][193] floats = 12,352 B  (aliases aS after the loop)
    __shared__ __align__(16) unsigned char smraw[12352];
    unsigned short* aS = (unsigned short*)smraw;
    float* sc = (float*)smraw;
    __shared__ float ssqS[16];

    const int tid  = threadIdx.x;
    const int row0 = blockIdx.x * 16;

    const int w  = tid >> 6, l = tid & 63;
    const int lm = l & 15,  lq = l >> 4;
    const bool roleT = (w < 2);
    const int cf0 = 2 * w;              // roleT topic frags cf0, cf0+1
    const int tf  = 2 + w;              // roleM topic frag (4 or 5)
    const int db  = 6 + 3 * (w - 2);    // roleM domain frags db..db+2
    const int sr = tid >> 4, kq = tid & 15;  // A staging: row 0..15, k-quad 0..15
    const int skf = kq >> 3, sk4 = kq & 7;   // kf half, 4-float group within half

    f32x4 acc0 = (f32x4)0.f, acc1 = (f32x4)0.f, acc2 = (f32x4)0.f, acc3 = (f32x4)0.f;
    float ssq = 0.f;

    const float* fbase = feat + (size_t)(row0 + sr) * 2048 + kq * 4;
    const unsigned short* lB = gB + l * 8;

    // convert+stage A (one float4/thread): fp32 -> f16 hi/lo planes, fused ssq
    auto cw = [&](int buf, float4 v) {
        ssq = fmaf(v.x, v.x, ssq); ssq = fmaf(v.y, v.y, ssq);
        ssq = fmaf(v.z, v.z, ssq); ssq = fmaf(v.w, v.w, ssq);
        H2U h0, h1, l0, l1;
        h0.h = __builtin_amdgcn_cvt_pkrtz(v.x, v.y);
        h1.h = __builtin_amdgcn_cvt_pkrtz(v.z, v.w);
        l0.h = __builtin_amdgcn_cvt_pkrtz(v.x - (float)h0.h[0], v.y - (float)h0.h[1]);
        l1.h = __builtin_amdgcn_cvt_pkrtz(v.z - (float)h1.h[0], v.w - (float)h1.h[1]);
        uint2 hi; hi.x = h0.u; hi.y = h1.u;
        uint2 lo; lo.x = l0.u; lo.y = l1.u;
        *(uint2*)(aS + (size_t)(((buf * 2 + 0) * 2 + skf) * 16 + sr) * 40 + sk4 * 4) = hi;
        *(uint2*)(aS + (size_t)(((buf * 2 + 1) * 2 + skf) * 16 + sr) * 40 + sk4 * 4) = lo;
    };

    // ---- B registers: named locals only (no arrays -> no scratch) ----
    uint4 b00, b01, b02, b03, b04;   // kf = 0
    uint4 b10, b11, b12, b13, b14;   // kf = 1

    // ---- prologue: stage A(0); A(1) and B(0) in flight ----
    {
        float4 c0 = *(const float4*)(fbase);
        LOADB(0);
        cw(0, c0);
    }
    float4 c1 = *(const float4*)(fbase + 64);
    sync_lds_only();

    for (int kt = 0; kt < 32; ++kt) {
        const int cb = kt & 1;

        // stage A(kt+1) into the other buffer (c1 loaded one iter ago)
        if (kt < 31) cw((kt + 1) & 1, c1);

        // A fragments from aS[cb]
        half8 fh0, fh1, fl0, fl1;
        {
            HU t0, t1, t2, t3;
            t0.u = *(const uint4*)(aS + (size_t)(((cb * 2 + 0) * 2 + 0) * 16 + lm) * 40 + lq * 8);
            t1.u = *(const uint4*)(aS + (size_t)(((cb * 2 + 0) * 2 + 1) * 16 + lm) * 40 + lq * 8);
            t2.u = *(const uint4*)(aS + (size_t)(((cb * 2 + 1) * 2 + 0) * 16 + lm) * 40 + lq * 8);
            t3.u = *(const uint4*)(aS + (size_t)(((cb * 2 + 1) * 2 + 1) * 16 + lm) * 40 + lq * 8);
            fh0 = t0.v; fh1 = t1.v; fl0 = t2.v; fl1 = t3.v;
        }

        // MFMA (per-acc order identical to R4)
        if (roleT) {
            HU hA, hB, hC, hD;
            hA.u = b00; hB.u = b01; hC.u = b02; hD.u = b03;
            acc0 = __builtin_amdgcn_mfma_f32_16x16x32_f16(fh0, hA.v, acc0, 0, 0, 0);
            acc0 = __builtin_amdgcn_mfma_f32_16x16x32_f16(fh0, hB.v, acc0, 0, 0, 0);
            acc0 = __builtin_amdgcn_mfma_f32_16x16x32_f16(fl0, hA.v, acc0, 0, 0, 0);
            acc1 = __builtin_amdgcn_mfma_f32_16x16x32_f16(fh0, hC.v, acc1, 0, 0, 0);
            acc1 = __builtin_amdgcn_mfma_f32_16x16x32_f16(fh0, hD.v, acc1, 0, 0, 0);
            acc1 = __builtin_amdgcn_mfma_f32_16x16x32_f16(fl0, hC.v, acc1, 0, 0, 0);
            hA.u = b10; hB.u = b11; hC.u = b12; hD.u = b13;
            acc0 = __builtin_amdgcn_mfma_f32_16x16x32_f16(fh1, hA.v, acc0, 0, 0, 0);
            acc0 = __builtin_amdgcn_mfma_f32_16x16x32_f16(fh1, hB.v, acc0, 0, 0, 0);
            acc0 = __builtin_amdgcn_mfma_f32_16x16x32_f16(fl1, hA.v, acc0, 0, 0, 0);
            acc1 = __builtin_amdgcn_mfma_f32_16x16x32_f16(fh1, hC.v, acc1, 0, 0, 0);
            acc1 = __builtin_amdgcn_mfma_f32_16x16x32_f16(fh1, hD.v, acc1, 0, 0, 0);
            acc1 = __builtin_amdgcn_mfma_f32_16x16x32_f16(fl1, hC.v, acc1, 0, 0, 0);
        } else {
            HU hA, hB, hC, hD, hE;
            hA.u = b00; hB.u = b01; hC.u = b02; hD.u = b03; hE.u = b04;
            acc0 = __builtin_amdgcn_mfma_f32_16x16x32_f16(fh0, hA.v, acc0, 0, 0, 0);
            acc0 = __builtin_amdgcn_mfma_f32_16x16x32_f16(fh0, hB.v, acc0, 0, 0, 0);
            acc0 = __builtin_amdgcn_mfma_f32_16x16x32_f16(fl0, hA.v, acc0, 0, 0, 0);
            acc1 = __builtin_amdgcn_mfma_f32_16x16x32_f16(fh0, hC.v, acc1, 0, 0, 0);
            acc2 = __builtin_amdgcn_mfma_f32_16x16x32_f16(fh0, hD.v, acc2, 0, 0, 0);
            acc3 = __builtin_amdgcn_mfma_f32_16x16x32_f16(fh0, hE.v, acc3, 0, 0, 0);
            hA.u = b10; hB.u = b11; hC.u = b12; hD.u = b13; hE.u = b14;
            acc0 = __builtin_amdgcn_mfma_f32_16x16x32_f16(fh1, hA.v, acc0, 0, 0, 0);
            acc0 = __builtin_amdgcn_mfma_f32_16x16x32_f16(fh1, hB.v, acc0, 0, 0, 0);
            acc0 = __builtin_amdgcn_mfma_f32_16x16x32_f16(fl1, hA.v, acc0, 0, 0, 0);
            acc1 = __builtin_amdgcn_mfma_f32_16x16x32_f16(fh1, hC.v, acc1, 0, 0, 0);
            acc2 = __builtin_amdgcn_mfma_f32_16x16x32_f16(fh1, hD.v, acc2, 0, 0, 0);
            acc3 = __builtin_amdgcn_mfma_f32_16x16x32_f16(fh1, hE.v, acc3, 0, 0, 0);
        }

        // in-place reloads for the NEXT iterations (issued after last use; ride
        // through the barrier — sync_lds_only never drains vmcnt)
        if (kt < 31) {
            LOADB(kt + 1);                                      // consumed in kt+1
            const int ka = (kt + 2 < 32) ? kt + 2 : 31;
            c1 = *(const float4*)(fbase + ka * 64);             // staged in kt+1
        }

        sync_lds_only();
    }

    // ---- scores -> LDS (aliases aS; safe after final barrier) ----
    if (roleT) {
        #pragma unroll
        for (int r4 = 0; r4 < 4; ++r4) {
            sc[(lq * 4 + r4) * 193 + cf0 * 16 + lm]       = acc0[r4];
            sc[(lq * 4 + r4) * 193 + (cf0 + 1) * 16 + lm] = acc1[r4];
        }
    } else {
        #pragma unroll
        for (int r4 = 0; r4 < 4; ++r4) {
            sc[(lq * 4 + r4) * 193 + tf * 16 + lm]        = acc0[r4];
            sc[(lq * 4 + r4) * 193 + db * 16 + lm]        = acc1[r4];
            sc[(lq * 4 + r4) * 193 + (db + 1) * 16 + lm]  = acc2[r4];
            sc[(lq * 4 + r4) * 193 + (db + 2) * 16 + lm]  = acc3[r4];
        }
    }

    // ssq: 16 staging threads per row (kq 0..15) -> full-row |feat|^2
    ssq += __shfl_xor(ssq, 1, 64);
    ssq += __shfl_xor(ssq, 2, 64);
    ssq += __shfl_xor(ssq, 4, 64);
    ssq += __shfl_xor(ssq, 8, 64);
    if ((l & 15) == 0) ssqS[w * 4 + (l >> 4)] = ssq;
    __syncthreads();

    // ---- softmax epilogue: 2 lanes per row (domains 0..4 / 5..8), wave 0 ----
    if (tid < 32) {
        const int rr = tid >> 1, hf = tid & 1;
        const int nd = hf ? 4 : 5;
        const int d0 = hf ? 5 : 0;
        const float inv = TAU_F / fmaxf(sqrtf(ssqS[rr]), 1e-12f);
        const float* scr = sc + (size_t)rr * 193;
        float lg[5];
        float dmax = -1e30f;
        #pragma unroll
        for (int dd = 0; dd < 5; ++dd) {
            if (dd < nd) {
                const int d = d0 + dd;
                const float* v = scr + d * 10;          // topic cols 0..89
                const float* u = scr + 96 + d * 10;     // domain cols 96..185
                float mx = v[0];
                #pragma unroll
                for (int m = 1; m < 10; ++m) mx = fmaxf(mx, v[m]);
                float ssum = 0.f, dot = 0.f;
                #pragma unroll
                for (int m = 0; m < 10; ++m) {
                    const float p = __expf((v[m] - mx) * inv);
                    ssum += p;
                    dot = fmaf(p, u[m], dot);
                }
                const float lgt = (dot / ssum) * inv;
                lg[dd] = lgt;
                dmax = fmaxf(dmax, lgt);
            } else {
                lg[dd] = -1e30f;                        // exp -> 0, doesn't affect sums
            }
        }
        dmax = fmaxf(dmax, __shfl_xor(dmax, 1, 64));
        float s2 = 0.f;
        #pragma unroll
        for (int dd = 0; dd < 5; ++dd) {
            const float p = __expf(lg[dd] - dmax);
            lg[dd] = p;
            s2 += p;
        }
        s2 += __shfl_xor(s2, 1, 64);
        const float r2 = 1.0f / s2;
        #pragma unroll
        for (int dd = 0; dd < 5; ++dd)
            if (dd < nd)
                out[(size_t)(row0 + rr) * 9 + d0 + dd] = lg[dd] * r2;
    }
}

extern "C" void kernel_launch(void* const* d_in, const int* in_sizes, int n_in,
                              void* d_out, int out_size, void* d_ws, size_t ws_size,
                              hipStream_t stream) {
    const float* feature = (const float*)d_in[0];
    const float* Wt      = (const float*)d_in[1];
    const float* Wd      = (const float*)d_in[2];
    const float* mem     = (const float*)d_in[3];
    const int*   cat     = (const int*)d_in[4];

    // ws layout: P (6.3 MB) | gB 1.57 MB @50331648
    float* P  = (float*)d_ws;
    unsigned short* gB = (unsigned short*)((char*)d_ws + 50331648);
    float* out = (float*)d_out;

    gproj2<<<256, 256, 0, stream>>>(Wt, Wd, mem, cat, P);
    split_g3<<<192, 256, 0, stream>>>(P, gB);
    fused_ep<<<1024, 256, 0, stream>>>(feature, gB, out);
}